// Round 1
// baseline (2937.425 us; speedup 1.0000x reference)
//
#include <hip/hip_runtime.h>
#include <hip/hip_bf16.h>
#include <stdint.h>

// ---------- types ----------
using f32x4  = __attribute__((ext_vector_type(4))) float;
using bf16x8 = __attribute__((ext_vector_type(8))) __bf16;
using short8 = __attribute__((ext_vector_type(8))) short;

__device__ __forceinline__ short f2b(float f) {
    unsigned u = __builtin_bit_cast(unsigned, f);
    unsigned r = (u + 0x7fff + ((u >> 16) & 1)) >> 16;   // RNE, no NaN inputs expected
    return (short)r;
}
__device__ __forceinline__ float b2f(short s) {
    unsigned u = ((unsigned)(unsigned short)s) << 16;
    return __builtin_bit_cast(float, u);
}
__device__ __forceinline__ float sigf(float x) { return 1.f / (1.f + __expf(-x)); }
__device__ __forceinline__ float tanhf_fast(float x) {
    x = fminf(fmaxf(x, -15.f), 15.f);
    float e = __expf(2.f * x);
    return (e - 1.f) / (e + 1.f);
}

// ---------- laneGate: laneC[s] = sigmoid(FC(1->32->1)) ----------
__global__ __launch_bounds__(256) void lanec_k(const float* lane, const float* W1, const float* b1,
                                               const float* W2, const float* b2, float* laneC) {
    int s = blockIdx.x * 256 + threadIdx.x;           // 4096
    float v = lane[s];
    float acc = b2[0];
    #pragma unroll
    for (int k = 0; k < 32; ++k) {
        float t = fmaxf(v * W1[k] + b1[k], 0.f);
        acc += t * W2[k];
    }
    laneC[s] = 1.f / (1.f + __expf(-acc));
}

// ---------- weight packing (bf16, combined gate weights) ----------
__global__ __launch_bounds__(256) void pack_k(const float* Wih, const float* Whh, const float* bih,
                                              const float* bhh, const float* oW, const float* fW1,
                                              const float* fW2, short* Wcomb, float* biasComb,
                                              short* oWp, short* fW1p, short* fW2p) {
    int i = blockIdx.x * 256 + threadIdx.x;
    if (i < 393216) {                                  // Wcomb [1024][384]
        int n = i / 384, k = i % 384;
        Wcomb[i] = f2b(k < 128 ? Wih[n * 128 + k] : Whh[n * 256 + (k - 128)]);
        return;
    }
    i -= 393216;
    if (i < 1024) { biasComb[i] = bih[i] + bhh[i]; return; }
    i -= 1024;
    if (i < 32768) { oWp[i] = f2b(oW[i]); return; }    // [128][256]
    i -= 32768;
    if (i < 32768) { fW1p[i] = f2b(fW1[i]); return; }  // [256][128]
    i -= 32768;
    if (i < 32768) {                                   // fW2p [128(pad)][256]
        int n = i / 256;
        fW2p[i] = (n < 64) ? f2b(fW2[i]) : (short)0;
        return;
    }
}

// ---------- embedding: xs[t][s][128] = bf16(relu(relu(x*laneC @ eW1.T+b) @ eW2.T + b)) ----------
__global__ __launch_bounds__(256) void embed_k(const float* inp, const float* laneC, const float* eW1,
                                               const float* eb1, const float* eW2, const float* eb2,
                                               short* xs) {
    __shared__ float sh1[4][64];
    int g = threadIdx.x >> 6, j = threadIdx.x & 63;
    int r = blockIdx.x * 4 + g;                        // r = s*64 + t
    int s = r >> 6, t = r & 63;
    float lc = laneC[s];
    float x0 = inp[(size_t)r * 3 + 0] * lc;
    float x1 = inp[(size_t)r * 3 + 1] * lc;
    float x2 = inp[(size_t)r * 3 + 2] * lc;
    float h = fmaxf(eW1[j * 3 + 0] * x0 + eW1[j * 3 + 1] * x1 + eW1[j * 3 + 2] * x2 + eb1[j], 0.f);
    sh1[g][j] = h;
    __syncthreads();
    float a0 = eb2[j], a1 = eb2[j + 64];
    #pragma unroll 8
    for (int k = 0; k < 64; ++k) {
        float hv = sh1[g][k];
        a0 += eW2[j * 64 + k] * hv;
        a1 += eW2[(j + 64) * 64 + k] * hv;
    }
    a0 = fmaxf(a0, 0.f); a1 = fmaxf(a1, 0.f);
    size_t base = ((size_t)t * 4096 + s) * 128;
    xs[base + j]      = f2b(a0);
    xs[base + j + 64] = f2b(a1);
}

// ---------- zero LSTM state ----------
__global__ __launch_bounds__(256) void init_k(float* cws, short* hb) {
    int i = blockIdx.x * 256 + threadIdx.x;            // 4096*256
    cws[i] = 0.f;
    hb[i] = 0;
}

// ---------- generic bf16 MFMA GEMM: C[M][N] = [A1|A2] @ B^T + bias ----------
// A1 [M][K1], A2 [M][K2] (may be null, K2=0), B [Npad][Kt] bf16 row-major, Kt=K1+K2.
// Tile 128x128, BK=32, 4 waves x (64x64). Writes f32 (stride Nstore) and/or bf16.
__global__ __launch_bounds__(256) void gemm_k(const short* A1, int K1, const short* A2, int K2,
                                              const short* B, int Kt, const float* bias,
                                              float* outF, short* outB, int Nstore, int Nreal,
                                              int relu) {
    __shared__ alignas(16) short As[128 * 32];
    __shared__ alignas(16) short Bs[128 * 32];
    int tid = threadIdx.x;
    int wave = tid >> 6, lane = tid & 63;
    int m0 = blockIdx.x * 128, n0 = blockIdx.y * 128;

    f32x4 acc[4][4];
    #pragma unroll
    for (int i = 0; i < 4; ++i)
        #pragma unroll
        for (int j = 0; j < 4; ++j) acc[i][j] = (f32x4){0.f, 0.f, 0.f, 0.f};

    const int lr = lane & 15, lk8 = (lane >> 4) * 8;
    const int am = (wave & 1) * 64, bn = (wave >> 1) * 64;
    const int row = tid >> 2, c8 = (tid & 3) * 8;      // staging chunk coords
    int nK = Kt / 32;

    for (int kt = 0; kt < nK; ++kt) {
        int kk = kt * 32;
        const short* Asrc; int astr, acol;
        if (kk < K1) { Asrc = A1; astr = K1; acol = kk; }
        else         { Asrc = A2; astr = K2; acol = kk - K1; }
        short8 a0 = *(const short8*)(Asrc + (size_t)(m0 + row) * astr + acol + c8);
        short8 a1 = *(const short8*)(Asrc + (size_t)(m0 + 64 + row) * astr + acol + c8);
        short8 b0 = *(const short8*)(B + (size_t)(n0 + row) * Kt + kk + c8);
        short8 b1 = *(const short8*)(B + (size_t)(n0 + 64 + row) * Kt + kk + c8);
        __syncthreads();                                // previous frag reads done
        *(short8*)&As[tid * 8] = a0;
        *(short8*)&As[(tid + 256) * 8] = a1;
        *(short8*)&Bs[tid * 8] = b0;
        *(short8*)&Bs[(tid + 256) * 8] = b1;
        __syncthreads();
        bf16x8 af[4], bfr[4];
        #pragma unroll
        for (int i = 0; i < 4; ++i) af[i]  = *(const bf16x8*)&As[(am + i * 16 + lr) * 32 + lk8];
        #pragma unroll
        for (int j = 0; j < 4; ++j) bfr[j] = *(const bf16x8*)&Bs[(bn + j * 16 + lr) * 32 + lk8];
        #pragma unroll
        for (int i = 0; i < 4; ++i)
            #pragma unroll
            for (int j = 0; j < 4; ++j)
                acc[i][j] = __builtin_amdgcn_mfma_f32_16x16x32_bf16(af[i], bfr[j], acc[i][j], 0, 0, 0);
    }

    int r0 = m0 + am + (lane >> 4) * 4;
    int c0 = n0 + bn + (lane & 15);
    #pragma unroll
    for (int j = 0; j < 4; ++j) {
        int col = c0 + j * 16;
        if (col >= Nreal) continue;
        float bs = bias[col];
        #pragma unroll
        for (int i = 0; i < 4; ++i) {
            #pragma unroll
            for (int r = 0; r < 4; ++r) {
                int rw = r0 + i * 16 + r;
                float v = acc[i][j][r] + bs;
                if (relu) v = fmaxf(v, 0.f);
                size_t o = (size_t)rw * Nstore + col;
                if (outF) outF[o] = v;
                if (outB) outB[o] = f2b(v);
            }
        }
    }
}

// ---------- per-step pointwise: gate activations + cell update + conv over hidden ----------
__global__ __launch_bounds__(256) void pointwise_k(const float* gates, float* cws, short* hb,
                                                   const float* convw, const float* convb,
                                                   float* Hdst, float* Cdst, short* predictb,
                                                   int tslot, int doWrite, int staged, int pslot) {
    __shared__ float sh[258];
    int s = blockIdx.x, j = threadIdx.x;
    size_t gbase = (size_t)s * 1024 + j;
    float gi = gates[gbase], gf = gates[gbase + 256], gg = gates[gbase + 512], go = gates[gbase + 768];
    size_t cidx = (size_t)s * 256 + j;
    float c = cws[cidx];
    c = sigf(gf) * c + sigf(gi) * tanhf_fast(gg);
    float hraw = sigf(go) * tanhf_fast(c);
    if (j == 0) { sh[0] = 0.f; sh[257] = 0.f; }
    sh[j + 1] = hraw;
    __syncthreads();
    float h = convw[0] * sh[j] + convw[1] * sh[j + 1] + convw[2] * sh[j + 2] + convb[0];
    cws[cidx] = c;
    hb[cidx] = f2b(h);
    if (doWrite) {
        size_t oidx = staged ? (((size_t)s * 64 + tslot) * 256 + j)
                             : (((size_t)s * 256 + j) * 64 + tslot);
        Hdst[oidx] = h;
        Cdst[oidx] = c;
    }
    if (pslot >= 0) predictb[((size_t)s * 16 + pslot) * 256 + j] = f2b(h);
}

// ---------- staged [s][t][j] -> output [s][j][t] transpose ----------
__global__ __launch_bounds__(256) void transpose_k(const float* Hs, const float* Cs,
                                                   float* Ho, float* Co) {
    __shared__ float tile[64][129];
    int s = blockIdx.x, jh = blockIdx.y;
    const float* src = blockIdx.z ? Cs : Hs;
    float* dst = blockIdx.z ? Co : Ho;
    #pragma unroll 4
    for (int i = 0; i < 32; ++i) {
        int idx = i * 256 + threadIdx.x;
        int t = idx >> 7, jj = idx & 127;
        tile[t][jj] = src[((size_t)s * 64 + t) * 256 + jh * 128 + jj];
    }
    __syncthreads();
    #pragma unroll 4
    for (int i = 0; i < 32; ++i) {
        int idx = i * 256 + threadIdx.x;
        int jj = idx >> 6, t = idx & 63;
        dst[((size_t)s * 256 + jh * 128 + jj) * 64 + t] = tile[t][jj];
    }
}

// ---------- final: fc3 (64->1) + divide by laneC ----------
__global__ __launch_bounds__(256) void final_k(const short* t2b, const float* fW3, const float* fb3,
                                               const float* laneC, float* out0) {
    int r = blockIdx.x * 256 + threadIdx.x;            // 65536
    float acc = fb3[0];
    const short* rowp = t2b + (size_t)r * 64;
    #pragma unroll 8
    for (int k = 0; k < 64; ++k) acc += b2f(rowp[k]) * fW3[k];
    out0[r] = acc / laneC[r >> 4];
}

// ---------- host ----------
extern "C" void kernel_launch(void* const* d_in, const int* in_sizes, int n_in,
                              void* d_out, int out_size, void* d_ws, size_t ws_size,
                              hipStream_t stream) {
    (void)in_sizes; (void)n_in; (void)out_size;
    const float* inputData = (const float*)d_in[0];
    const float* lane  = (const float*)d_in[1];
    const float* lgW1  = (const float*)d_in[2];  const float* lgb1 = (const float*)d_in[3];
    const float* lgW2  = (const float*)d_in[4];  const float* lgb2 = (const float*)d_in[5];
    const float* eW1   = (const float*)d_in[6];  const float* eb1  = (const float*)d_in[7];
    const float* eW2   = (const float*)d_in[8];  const float* eb2  = (const float*)d_in[9];
    const float* Wih   = (const float*)d_in[10]; const float* Whh  = (const float*)d_in[11];
    const float* bih   = (const float*)d_in[12]; const float* bhh  = (const float*)d_in[13];
    const float* convw = (const float*)d_in[14]; const float* convb= (const float*)d_in[15];
    const float* oW    = (const float*)d_in[16]; const float* ob   = (const float*)d_in[17];
    const float* fW1   = (const float*)d_in[18]; const float* fb1  = (const float*)d_in[19];
    const float* fW2   = (const float*)d_in[20]; const float* fb2  = (const float*)d_in[21];
    const float* fW3   = (const float*)d_in[22]; const float* fb3  = (const float*)d_in[23];

    float* out0 = (float*)d_out;
    float* Hout = out0 + 65536;
    float* Cout = Hout + (size_t)67108864;

    char* w = (char*)d_ws;
    size_t off = 0;
    auto alloc = [&](size_t bytes) -> void* {
        void* p = w + off;
        off += (bytes + 255) & ~(size_t)255;
        return p;
    };
    float* laneC    = (float*)alloc(4096 * 4);
    float* biasComb = (float*)alloc(1024 * 4);
    short* Wcomb    = (short*)alloc((size_t)1024 * 384 * 2);
    short* oWp      = (short*)alloc((size_t)128 * 256 * 2);
    short* fW1p     = (short*)alloc((size_t)256 * 128 * 2);
    short* fW2p     = (short*)alloc((size_t)128 * 256 * 2);
    short* xs       = (short*)alloc((size_t)64 * 4096 * 128 * 2);
    short* hb       = (short*)alloc((size_t)4096 * 256 * 2);
    float* cws      = (float*)alloc((size_t)4096 * 256 * 4);
    float* gates    = (float*)alloc((size_t)4096 * 1024 * 4);
    short* predictb = (short*)alloc((size_t)65536 * 256 * 2);
    short* t0b      = (short*)alloc((size_t)65536 * 128 * 2);
    short* t1b      = (short*)alloc((size_t)65536 * 256 * 2);
    short* t2b      = (short*)alloc((size_t)65536 * 64 * 2);
    float* Hstage   = (float*)alloc((size_t)4096 * 64 * 256 * 4);
    float* Cstage   = (float*)alloc((size_t)4096 * 64 * 256 * 4);
    bool staged = ws_size >= off;

    lanec_k<<<16, 256, 0, stream>>>(lane, lgW1, lgb1, lgW2, lgb2, laneC);
    {
        int total = 393216 + 1024 + 32768 + 32768 + 32768;
        pack_k<<<(total + 255) / 256, 256, 0, stream>>>(Wih, Whh, bih, bhh, oW, fW1, fW2,
                                                        Wcomb, biasComb, oWp, fW1p, fW2p);
    }
    embed_k<<<65536, 256, 0, stream>>>(inputData, laneC, eW1, eb1, eW2, eb2, xs);
    init_k<<<4096, 256, 0, stream>>>(cws, hb);

    for (int k = 0; k < 65; ++k) {
        int it = (k <= 48) ? k : k - 1;
        gemm_k<<<dim3(32, 8), 256, 0, stream>>>(xs + (size_t)it * 4096 * 128, 128, hb, 256,
                                                Wcomb, 384, biasComb, gates, (short*)nullptr,
                                                1024, 1024, 0);
        int tslot = (k < 48) ? k : k - 1;
        int doW = (k == 48) ? 0 : 1;
        int pslot = (k >= 49) ? (k - 49) : -1;
        float* Hd = staged ? Hstage : Hout;
        float* Cd = staged ? Cstage : Cout;
        pointwise_k<<<4096, 256, 0, stream>>>(gates, cws, hb, convw, convb, Hd, Cd, predictb,
                                              tslot, doW, staged ? 1 : 0, pslot);
    }
    if (staged)
        transpose_k<<<dim3(4096, 2, 2), 256, 0, stream>>>(Hstage, Cstage, Hout, Cout);

    gemm_k<<<dim3(512, 1), 256, 0, stream>>>(predictb, 256, (const short*)nullptr, 0, oWp, 256,
                                             ob, (float*)nullptr, t0b, 128, 128, 0);
    gemm_k<<<dim3(512, 2), 256, 0, stream>>>(t0b, 128, (const short*)nullptr, 0, fW1p, 128,
                                             fb1, (float*)nullptr, t1b, 256, 256, 1);
    gemm_k<<<dim3(512, 1), 256, 0, stream>>>(t1b, 256, (const short*)nullptr, 0, fW2p, 256,
                                             fb2, (float*)nullptr, t2b, 64, 64, 1);
    final_k<<<256, 256, 0, stream>>>(t2b, fW3, fb3, laneC, out0);
}

// Round 2
// 2099.825 us; speedup vs baseline: 1.3989x; 1.3989x over previous
//
#include <hip/hip_runtime.h>
#include <hip/hip_bf16.h>
#include <stdint.h>

// ---------- types ----------
using f32x4  = __attribute__((ext_vector_type(4))) float;
using bf16x8 = __attribute__((ext_vector_type(8))) __bf16;
using short8 = __attribute__((ext_vector_type(8))) short;

__device__ __forceinline__ short f2b(float f) {
    unsigned u = __builtin_bit_cast(unsigned, f);
    unsigned r = (u + 0x7fff + ((u >> 16) & 1)) >> 16;   // RNE, no NaN inputs expected
    return (short)r;
}
__device__ __forceinline__ float b2f(short s) {
    unsigned u = ((unsigned)(unsigned short)s) << 16;
    return __builtin_bit_cast(float, u);
}
__device__ __forceinline__ float sigf(float x) { return 1.f / (1.f + __expf(-x)); }
__device__ __forceinline__ float tanhf_fast(float x) {
    x = fminf(fmaxf(x, -15.f), 15.f);
    float e = __expf(2.f * x);
    return (e - 1.f) / (e + 1.f);
}

// ---------- laneGate: laneC[s] = sigmoid(FC(1->32->1)) ----------
__global__ __launch_bounds__(256) void lanec_k(const float* lane, const float* W1, const float* b1,
                                               const float* W2, const float* b2, float* laneC) {
    int s = blockIdx.x * 256 + threadIdx.x;           // 4096
    float v = lane[s];
    float acc = b2[0];
    #pragma unroll
    for (int k = 0; k < 32; ++k) {
        float t = fmaxf(v * W1[k] + b1[k], 0.f);
        acc += t * W2[k];
    }
    laneC[s] = 1.f / (1.f + __expf(-acc));
}

// ---------- weight packing (bf16, combined gate weights) ----------
__global__ __launch_bounds__(256) void pack_k(const float* Wih, const float* Whh, const float* bih,
                                              const float* bhh, const float* oW, const float* fW1,
                                              const float* fW2, const float* eW2,
                                              short* Wcomb, float* biasComb,
                                              short* oWp, short* fW1p, short* fW2p, short* eW2p) {
    int i = blockIdx.x * 256 + threadIdx.x;
    if (i < 393216) {                                  // Wcomb [1024][384]
        int n = i / 384, k = i % 384;
        Wcomb[i] = f2b(k < 128 ? Wih[n * 128 + k] : Whh[n * 256 + (k - 128)]);
        return;
    }
    i -= 393216;
    if (i < 1024) { biasComb[i] = bih[i] + bhh[i]; return; }
    i -= 1024;
    if (i < 32768) { oWp[i] = f2b(oW[i]); return; }    // [128][256]
    i -= 32768;
    if (i < 32768) { fW1p[i] = f2b(fW1[i]); return; }  // [256][128]
    i -= 32768;
    if (i < 32768) {                                   // fW2p [128(pad)][256]
        int n = i / 256;
        fW2p[i] = (n < 64) ? f2b(fW2[i]) : (short)0;
        return;
    }
    i -= 32768;
    if (i < 8192) { eW2p[i] = f2b(eW2[i]); return; }   // [128][64]
}

// ---------- embedding layer 1: h1[t][s][64] = bf16(relu(x*laneC @ eW1.T + eb1)) ----------
__global__ __launch_bounds__(256) void embed1_k(const float* inp, const float* laneC,
                                                const float* eW1, const float* eb1, short* h1) {
    int g = threadIdx.x >> 6, j = threadIdx.x & 63;
    int t = blockIdx.x >> 10;
    int s = ((blockIdx.x & 1023) << 2) + g;
    float lc = laneC[s];
    size_t rin = ((size_t)s * 64 + t) * 3;
    float x0 = inp[rin] * lc, x1 = inp[rin + 1] * lc, x2 = inp[rin + 2] * lc;
    float h = fmaxf(eW1[j * 3] * x0 + eW1[j * 3 + 1] * x1 + eW1[j * 3 + 2] * x2 + eb1[j], 0.f);
    h1[((size_t)t * 4096 + s) * 64 + j] = f2b(h);
}

// ---------- zero LSTM state ----------
__global__ __launch_bounds__(256) void init_k(float* cws, short* hb) {
    int i = blockIdx.x * 256 + threadIdx.x;            // 4096*256
    cws[i] = 0.f;
    hb[i] = 0;
}

// ---------- generic bf16 MFMA GEMM: C[M][N] = [A1|A2] @ B^T + bias ----------
// A1 [M][K1], A2 [M][K2] (may be null, K2=0), B [Npad][Kt] bf16 row-major, Kt=K1+K2.
// Tile 128x128, BK=32, 4 waves x (64x64). Writes f32 (stride Nstore) and/or bf16.
__global__ __launch_bounds__(256) void gemm_k(const short* A1, int K1, const short* A2, int K2,
                                              const short* B, int Kt, const float* bias,
                                              float* outF, short* outB, int Nstore, int Nreal,
                                              int relu) {
    __shared__ alignas(16) short As[128 * 32];
    __shared__ alignas(16) short Bs[128 * 32];
    int tid = threadIdx.x;
    int wave = tid >> 6, lane = tid & 63;
    int m0 = blockIdx.x * 128, n0 = blockIdx.y * 128;

    f32x4 acc[4][4];
    #pragma unroll
    for (int i = 0; i < 4; ++i)
        #pragma unroll
        for (int j = 0; j < 4; ++j) acc[i][j] = (f32x4){0.f, 0.f, 0.f, 0.f};

    const int lr = lane & 15, lk8 = (lane >> 4) * 8;
    const int am = (wave & 1) * 64, bn = (wave >> 1) * 64;
    const int row = tid >> 2, c8 = (tid & 3) * 8;      // staging chunk coords
    int nK = Kt / 32;

    for (int kt = 0; kt < nK; ++kt) {
        int kk = kt * 32;
        const short* Asrc; int astr, acol;
        if (kk < K1) { Asrc = A1; astr = K1; acol = kk; }
        else         { Asrc = A2; astr = K2; acol = kk - K1; }
        short8 a0 = *(const short8*)(Asrc + (size_t)(m0 + row) * astr + acol + c8);
        short8 a1 = *(const short8*)(Asrc + (size_t)(m0 + 64 + row) * astr + acol + c8);
        short8 b0 = *(const short8*)(B + (size_t)(n0 + row) * Kt + kk + c8);
        short8 b1 = *(const short8*)(B + (size_t)(n0 + 64 + row) * Kt + kk + c8);
        __syncthreads();                                // previous frag reads done
        *(short8*)&As[tid * 8] = a0;
        *(short8*)&As[(tid + 256) * 8] = a1;
        *(short8*)&Bs[tid * 8] = b0;
        *(short8*)&Bs[(tid + 256) * 8] = b1;
        __syncthreads();
        bf16x8 af[4], bfr[4];
        #pragma unroll
        for (int i = 0; i < 4; ++i) af[i]  = *(const bf16x8*)&As[(am + i * 16 + lr) * 32 + lk8];
        #pragma unroll
        for (int j = 0; j < 4; ++j) bfr[j] = *(const bf16x8*)&Bs[(bn + j * 16 + lr) * 32 + lk8];
        #pragma unroll
        for (int i = 0; i < 4; ++i)
            #pragma unroll
            for (int j = 0; j < 4; ++j)
                acc[i][j] = __builtin_amdgcn_mfma_f32_16x16x32_bf16(af[i], bfr[j], acc[i][j], 0, 0, 0);
    }

    int r0 = m0 + am + (lane >> 4) * 4;
    int c0 = n0 + bn + (lane & 15);
    #pragma unroll
    for (int j = 0; j < 4; ++j) {
        int col = c0 + j * 16;
        if (col >= Nreal) continue;
        float bs = bias[col];
        #pragma unroll
        for (int i = 0; i < 4; ++i) {
            #pragma unroll
            for (int r = 0; r < 4; ++r) {
                int rw = r0 + i * 16 + r;
                float v = acc[i][j][r] + bs;
                if (relu) v = fmaxf(v, 0.f);
                size_t o = (size_t)rw * Nstore + col;
                if (outF) outF[o] = v;
                if (outB) outB[o] = f2b(v);
            }
        }
    }
}

// ---------- per-step pointwise: gate activations + cell update + conv over hidden ----------
__global__ __launch_bounds__(256) void pointwise_k(const float* gates, float* cws, short* hb,
                                                   const float* convw, const float* convb,
                                                   float* Hdst, float* Cdst, short* predictb,
                                                   int tslot, int doWrite, int staged, int pslot) {
    __shared__ float sh[258];
    int s = blockIdx.x, j = threadIdx.x;
    size_t gbase = (size_t)s * 1024 + j;
    float gi = gates[gbase], gf = gates[gbase + 256], gg = gates[gbase + 512], go = gates[gbase + 768];
    size_t cidx = (size_t)s * 256 + j;
    float c = cws[cidx];
    c = sigf(gf) * c + sigf(gi) * tanhf_fast(gg);
    float hraw = sigf(go) * tanhf_fast(c);
    if (j == 0) { sh[0] = 0.f; sh[257] = 0.f; }
    sh[j + 1] = hraw;
    __syncthreads();
    float h = convw[0] * sh[j] + convw[1] * sh[j + 1] + convw[2] * sh[j + 2] + convb[0];
    cws[cidx] = c;
    hb[cidx] = f2b(h);
    if (doWrite) {
        size_t oidx = staged ? (((size_t)s * 64 + tslot) * 256 + j)
                             : (((size_t)s * 256 + j) * 64 + tslot);
        Hdst[oidx] = h;
        Cdst[oidx] = c;
    }
    if (pslot >= 0) predictb[((size_t)s * 16 + pslot) * 256 + j] = f2b(h);
}

// ---------- staged [s][t][j] -> output [s][j][t] transpose ----------
__global__ __launch_bounds__(256) void transpose_k(const float* Hs, const float* Cs,
                                                   float* Ho, float* Co) {
    __shared__ float tile[64][129];
    int s = blockIdx.x, jh = blockIdx.y;
    const float* src = blockIdx.z ? Cs : Hs;
    float* dst = blockIdx.z ? Co : Ho;
    #pragma unroll 4
    for (int i = 0; i < 32; ++i) {
        int idx = i * 256 + threadIdx.x;
        int t = idx >> 7, jj = idx & 127;
        tile[t][jj] = src[((size_t)s * 64 + t) * 256 + jh * 128 + jj];
    }
    __syncthreads();
    #pragma unroll 4
    for (int i = 0; i < 32; ++i) {
        int idx = i * 256 + threadIdx.x;
        int jj = idx >> 6, t = idx & 63;
        dst[((size_t)s * 256 + jh * 128 + jj) * 64 + t] = tile[t][jj];
    }
}

// ---------- final: fc3 (64->1) + divide by laneC ----------
__global__ __launch_bounds__(256) void final_k(const short* t2b, const float* fW3, const float* fb3,
                                               const float* laneC, float* out0) {
    int r = blockIdx.x * 256 + threadIdx.x;            // 65536
    float acc = fb3[0];
    const short* rowp = t2b + (size_t)r * 64;
    #pragma unroll 8
    for (int k = 0; k < 64; ++k) acc += b2f(rowp[k]) * fW3[k];
    out0[r] = acc / laneC[r >> 4];
}

// ---------- host ----------
extern "C" void kernel_launch(void* const* d_in, const int* in_sizes, int n_in,
                              void* d_out, int out_size, void* d_ws, size_t ws_size,
                              hipStream_t stream) {
    (void)in_sizes; (void)n_in; (void)out_size;
    const float* inputData = (const float*)d_in[0];
    const float* lane  = (const float*)d_in[1];
    const float* lgW1  = (const float*)d_in[2];  const float* lgb1 = (const float*)d_in[3];
    const float* lgW2  = (const float*)d_in[4];  const float* lgb2 = (const float*)d_in[5];
    const float* eW1   = (const float*)d_in[6];  const float* eb1  = (const float*)d_in[7];
    const float* eW2   = (const float*)d_in[8];  const float* eb2  = (const float*)d_in[9];
    const float* Wih   = (const float*)d_in[10]; const float* Whh  = (const float*)d_in[11];
    const float* bih   = (const float*)d_in[12]; const float* bhh  = (const float*)d_in[13];
    const float* convw = (const float*)d_in[14]; const float* convb= (const float*)d_in[15];
    const float* oW    = (const float*)d_in[16]; const float* ob   = (const float*)d_in[17];
    const float* fW1   = (const float*)d_in[18]; const float* fb1  = (const float*)d_in[19];
    const float* fW2   = (const float*)d_in[20]; const float* fb2  = (const float*)d_in[21];
    const float* fW3   = (const float*)d_in[22]; const float* fb3  = (const float*)d_in[23];

    float* out0 = (float*)d_out;
    float* Hout = out0 + 65536;
    float* Cout = Hout + (size_t)67108864;

    char* w = (char*)d_ws;
    size_t off = 0;
    auto alloc = [&](size_t bytes) -> void* {
        void* p = w + off;
        off += (bytes + 255) & ~(size_t)255;
        return p;
    };
    float* laneC    = (float*)alloc(4096 * 4);
    float* biasComb = (float*)alloc(1024 * 4);
    short* Wcomb    = (short*)alloc((size_t)1024 * 384 * 2);
    short* oWp      = (short*)alloc((size_t)128 * 256 * 2);
    short* fW1p     = (short*)alloc((size_t)256 * 128 * 2);
    short* fW2p     = (short*)alloc((size_t)128 * 256 * 2);
    short* eW2p     = (short*)alloc((size_t)128 * 64 * 2);
    short* h1       = (short*)alloc((size_t)64 * 4096 * 64 * 2);
    short* xs       = (short*)alloc((size_t)64 * 4096 * 128 * 2);
    short* hb       = (short*)alloc((size_t)4096 * 256 * 2);
    float* cws      = (float*)alloc((size_t)4096 * 256 * 4);
    float* gates    = (float*)alloc((size_t)4096 * 1024 * 4);
    short* predictb = (short*)alloc((size_t)65536 * 256 * 2);
    short* t0b      = (short*)alloc((size_t)65536 * 128 * 2);
    short* t1b      = (short*)alloc((size_t)65536 * 256 * 2);
    short* t2b      = (short*)alloc((size_t)65536 * 64 * 2);
    float* Hstage   = (float*)alloc((size_t)4096 * 64 * 256 * 4);
    float* Cstage   = (float*)alloc((size_t)4096 * 64 * 256 * 4);
    bool staged = ws_size >= off;

    lanec_k<<<16, 256, 0, stream>>>(lane, lgW1, lgb1, lgW2, lgb2, laneC);
    {
        int total = 393216 + 1024 + 32768 + 32768 + 32768 + 8192;
        pack_k<<<(total + 255) / 256, 256, 0, stream>>>(Wih, Whh, bih, bhh, oW, fW1, fW2, eW2,
                                                        Wcomb, biasComb, oWp, fW1p, fW2p, eW2p);
    }
    embed1_k<<<65536, 256, 0, stream>>>(inputData, laneC, eW1, eb1, h1);
    // embedding layer 2 as MFMA GEMM: [262144 x 64] @ eW2^T -> relu -> bf16 xs[t][s][128]
    gemm_k<<<dim3(2048, 1), 256, 0, stream>>>(h1, 64, (const short*)nullptr, 0, eW2p, 64,
                                              eb2, (float*)nullptr, xs, 128, 128, 1);
    init_k<<<4096, 256, 0, stream>>>(cws, hb);

    for (int k = 0; k < 65; ++k) {
        int it = (k <= 48) ? k : k - 1;
        gemm_k<<<dim3(32, 8), 256, 0, stream>>>(xs + (size_t)it * 4096 * 128, 128, hb, 256,
                                                Wcomb, 384, biasComb, gates, (short*)nullptr,
                                                1024, 1024, 0);
        int tslot = (k < 48) ? k : k - 1;
        int doW = (k == 48) ? 0 : 1;
        int pslot = (k >= 49) ? (k - 49) : -1;
        float* Hd = staged ? Hstage : Hout;
        float* Cd = staged ? Cstage : Cout;
        pointwise_k<<<4096, 256, 0, stream>>>(gates, cws, hb, convw, convb, Hd, Cd, predictb,
                                              tslot, doW, staged ? 1 : 0, pslot);
    }
    if (staged)
        transpose_k<<<dim3(4096, 2, 2), 256, 0, stream>>>(Hstage, Cstage, Hout, Cout);

    gemm_k<<<dim3(512, 1), 256, 0, stream>>>(predictb, 256, (const short*)nullptr, 0, oWp, 256,
                                             ob, (float*)nullptr, t0b, 128, 128, 0);
    gemm_k<<<dim3(512, 2), 256, 0, stream>>>(t0b, 128, (const short*)nullptr, 0, fW1p, 128,
                                             fb1, (float*)nullptr, t1b, 256, 256, 1);
    gemm_k<<<dim3(512, 1), 256, 0, stream>>>(t1b, 256, (const short*)nullptr, 0, fW2p, 256,
                                             fb2, (float*)nullptr, t2b, 64, 64, 1);
    final_k<<<256, 256, 0, stream>>>(t2b, fW3, fb3, laneC, out0);
}

// Round 3
// 1724.588 us; speedup vs baseline: 1.7033x; 1.2176x over previous
//
#include <hip/hip_runtime.h>
#include <hip/hip_bf16.h>
#include <stdint.h>

// ---------- types ----------
using f32x4  = __attribute__((ext_vector_type(4))) float;
using bf16x8 = __attribute__((ext_vector_type(8))) __bf16;
using short8 = __attribute__((ext_vector_type(8))) short;

__device__ __forceinline__ short f2b(float f) {
    unsigned u = __builtin_bit_cast(unsigned, f);
    unsigned r = (u + 0x7fff + ((u >> 16) & 1)) >> 16;   // RNE
    return (short)r;
}
__device__ __forceinline__ float b2f(short s) {
    unsigned u = ((unsigned)(unsigned short)s) << 16;
    return __builtin_bit_cast(float, u);
}
__device__ __forceinline__ float sigf(float x) {
    return __builtin_amdgcn_rcpf(1.f + __expf(-x));
}
__device__ __forceinline__ float tanhf_fast(float x) {
    x = fminf(fmaxf(x, -15.f), 15.f);
    // tanh(x) = 2/(1+exp(-2x)) - 1
    return 2.f * __builtin_amdgcn_rcpf(1.f + __expf(-2.f * x)) - 1.f;
}

// ---------- laneGate ----------
__global__ __launch_bounds__(256) void lanec_k(const float* lane, const float* W1, const float* b1,
                                               const float* W2, const float* b2, float* laneC) {
    int s = blockIdx.x * 256 + threadIdx.x;
    float v = lane[s];
    float acc = b2[0];
    #pragma unroll
    for (int k = 0; k < 32; ++k) {
        float t = fmaxf(v * W1[k] + b1[k], 0.f);
        acc += t * W2[k];
    }
    laneC[s] = 1.f / (1.f + __expf(-acc));
}

// ---------- weight packing ----------
// pW rows permuted: p = 64*w + 16*g + (j&15), where w=j>>4 (j-slice), g=gate.
// Original combined row n = g*256 + j;  K layout: [0..128)=Wih cols, [128..384)=Whh cols.
__global__ __launch_bounds__(256) void pack_k(const float* Wih, const float* Whh, const float* bih,
                                              const float* bhh, const float* oW, const float* fW1,
                                              const float* fW2, const float* eW2,
                                              short* pW, float* biasP,
                                              short* oWp, short* fW1p, short* fW2p, short* eW2p) {
    int i = blockIdx.x * 256 + threadIdx.x;
    if (i < 393216) {                                  // pW [1024][384]
        int p = i / 384, k = i % 384;
        int g = (p >> 4) & 3;
        int j = ((p >> 6) << 4) | (p & 15);
        int n = g * 256 + j;
        pW[i] = f2b(k < 128 ? Wih[n * 128 + k] : Whh[n * 256 + (k - 128)]);
        return;
    }
    i -= 393216;
    if (i < 1024) {                                    // biasP (same permuted order)
        int p = i;
        int g = (p >> 4) & 3;
        int j = ((p >> 6) << 4) | (p & 15);
        int n = g * 256 + j;
        biasP[p] = bih[n] + bhh[n];
        return;
    }
    i -= 1024;
    if (i < 32768) { oWp[i] = f2b(oW[i]); return; }    // [128][256]
    i -= 32768;
    if (i < 32768) { fW1p[i] = f2b(fW1[i]); return; }  // [256][128]
    i -= 32768;
    if (i < 32768) {                                   // fW2p [128(pad)][256]
        int n = i / 256;
        fW2p[i] = (n < 64) ? f2b(fW2[i]) : (short)0;
        return;
    }
    i -= 32768;
    if (i < 8192) { eW2p[i] = f2b(eW2[i]); return; }   // [128][64]
}

// ---------- embedding layer 1 ----------
__global__ __launch_bounds__(256) void embed1_k(const float* inp, const float* laneC,
                                                const float* eW1, const float* eb1, short* h1) {
    int g = threadIdx.x >> 6, j = threadIdx.x & 63;
    int t = blockIdx.x >> 10;
    int s = ((blockIdx.x & 1023) << 2) + g;
    float lc = laneC[s];
    size_t rin = ((size_t)s * 64 + t) * 3;
    float x0 = inp[rin] * lc, x1 = inp[rin + 1] * lc, x2 = inp[rin + 2] * lc;
    float h = fmaxf(eW1[j * 3] * x0 + eW1[j * 3 + 1] * x1 + eW1[j * 3 + 2] * x2 + eb1[j], 0.f);
    h1[((size_t)t * 4096 + s) * 64 + j] = f2b(h);
}

// ---------- generic bf16 MFMA GEMM (embed layer2 + head) ----------
__global__ __launch_bounds__(256) void gemm_k(const short* A1, int K1, const short* A2, int K2,
                                              const short* B, int Kt, const float* bias,
                                              float* outF, short* outB, int Nstore, int Nreal,
                                              int relu) {
    __shared__ alignas(16) short As[128 * 32];
    __shared__ alignas(16) short Bs[128 * 32];
    int tid = threadIdx.x;
    int wave = tid >> 6, lane = tid & 63;
    int m0 = blockIdx.x * 128, n0 = blockIdx.y * 128;

    f32x4 acc[4][4];
    #pragma unroll
    for (int i = 0; i < 4; ++i)
        #pragma unroll
        for (int j = 0; j < 4; ++j) acc[i][j] = (f32x4){0.f, 0.f, 0.f, 0.f};

    const int lr = lane & 15, lk8 = (lane >> 4) * 8;
    const int am = (wave & 1) * 64, bn = (wave >> 1) * 64;
    const int row = tid >> 2, c8 = (tid & 3) * 8;
    int nK = Kt / 32;

    for (int kt = 0; kt < nK; ++kt) {
        int kk = kt * 32;
        const short* Asrc; int astr, acol;
        if (kk < K1) { Asrc = A1; astr = K1; acol = kk; }
        else         { Asrc = A2; astr = K2; acol = kk - K1; }
        short8 a0 = *(const short8*)(Asrc + (size_t)(m0 + row) * astr + acol + c8);
        short8 a1 = *(const short8*)(Asrc + (size_t)(m0 + 64 + row) * astr + acol + c8);
        short8 b0 = *(const short8*)(B + (size_t)(n0 + row) * Kt + kk + c8);
        short8 b1 = *(const short8*)(B + (size_t)(n0 + 64 + row) * Kt + kk + c8);
        __syncthreads();
        *(short8*)&As[tid * 8] = a0;
        *(short8*)&As[(tid + 256) * 8] = a1;
        *(short8*)&Bs[tid * 8] = b0;
        *(short8*)&Bs[(tid + 256) * 8] = b1;
        __syncthreads();
        bf16x8 af[4], bfr[4];
        #pragma unroll
        for (int i = 0; i < 4; ++i) af[i]  = *(const bf16x8*)&As[(am + i * 16 + lr) * 32 + lk8];
        #pragma unroll
        for (int j = 0; j < 4; ++j) bfr[j] = *(const bf16x8*)&Bs[(bn + j * 16 + lr) * 32 + lk8];
        #pragma unroll
        for (int i = 0; i < 4; ++i)
            #pragma unroll
            for (int j = 0; j < 4; ++j)
                acc[i][j] = __builtin_amdgcn_mfma_f32_16x16x32_bf16(af[i], bfr[j], acc[i][j], 0, 0, 0);
    }

    int r0 = m0 + am + (lane >> 4) * 4;
    int c0 = n0 + bn + (lane & 15);
    #pragma unroll
    for (int j = 0; j < 4; ++j) {
        int col = c0 + j * 16;
        if (col >= Nreal) continue;
        float bs = bias[col];
        #pragma unroll
        for (int i = 0; i < 4; ++i) {
            #pragma unroll
            for (int r = 0; r < 4; ++r) {
                int rw = r0 + i * 16 + r;
                float v = acc[i][j][r] + bs;
                if (relu) v = fmaxf(v, 0.f);
                size_t o = (size_t)rw * Nstore + col;
                if (outF) outF[o] = v;
                if (outB) outB[o] = f2b(v);
            }
        }
    }
}

// ---------- persistent fused LSTM ----------
// 256 blocks x 1024 threads (16 waves). Block owns 16 s-rows, runs all 65 steps.
// Wave w owns j in [16w,16w+16); its 4 MFMA col-frags are the 4 gates of those j.
// W register-resident (192 VGPR/lane); c in 4 VGPR/lane; h in LDS (A-operand K=[128,384)).
__global__ __launch_bounds__(1024) void lstm_k(const short* xs, const short* pW, const float* biasP,
                                               const float* convw, const float* convb,
                                               float* Hd, float* Cd, short* predictb, int staged) {
    __shared__ alignas(16) short A[16][392];    // [s][k]: k 0..127 = xs, 128..383 = h(bf16)
    __shared__ float hraw[16][258];             // conv halo buffer

    const int tid = threadIdx.x;
    const int w = tid >> 6, l = tid & 63;
    const int lj = l & 15, lk = l >> 4;
    const int j = (w << 4) | lj;                // 0..255 hidden index this lane owns
    const int s4 = lk * 4;                      // local row base for acc rows
    const int s0 = blockIdx.x * 16;

    // ---- prefill W into registers ----
    bf16x8 wreg[4][12];
    #pragma unroll
    for (int g = 0; g < 4; ++g)
        #pragma unroll
        for (int kk = 0; kk < 12; ++kk)
            wreg[g][kk] = *(const bf16x8*)(pW + ((size_t)(64 * w + 16 * g + lj)) * 384 + kk * 32 + lk * 8);
    float bias_g[4];
    #pragma unroll
    for (int g = 0; g < 4; ++g) bias_g[g] = biasP[64 * w + 16 * g + lj];
    float creg[4] = {0.f, 0.f, 0.f, 0.f};
    const float cw0 = convw[0], cw1 = convw[1], cw2 = convw[2], cb = convb[0];

    // ---- zero h region of A; zero hraw halo columns ----
    for (int i = tid; i < 16 * 256; i += 1024) A[i >> 8][128 + (i & 255)] = 0;
    if (tid < 16) { hraw[tid][0] = 0.f; hraw[tid][257] = 0.f; }

    for (int k = 0; k < 65; ++k) {
        int it = (k <= 48) ? k : k - 1;
        // S1: stream xs tile [16][128] bf16 (one u32 per thread)
        {
            int r = tid >> 6, c2 = (tid & 63) * 2;
            *(int*)&A[r][c2] = *(const int*)(xs + ((size_t)it * 4096 + s0 + r) * 128 + c2);
        }
        __syncthreads();    // xs + (prev) h writes visible; prev hraw reads done

        // S3: gates = [xs|h] @ W^T + bias  (per lane: 4 gates x 4 s-rows)
        f32x4 acc[4];
        #pragma unroll
        for (int g = 0; g < 4; ++g) acc[g] = (f32x4){bias_g[g], bias_g[g], bias_g[g], bias_g[g]};
        #pragma unroll
        for (int kk = 0; kk < 12; ++kk) {
            bf16x8 af = *(const bf16x8*)&A[lj][kk * 32 + lk * 8];
            #pragma unroll
            for (int g = 0; g < 4; ++g)
                acc[g] = __builtin_amdgcn_mfma_f32_16x16x32_bf16(af, wreg[g][kk], acc[g], 0, 0, 0);
        }

        // S5: cell update (register-local), hraw -> LDS
        #pragma unroll
        for (int r = 0; r < 4; ++r) {
            float gi = acc[0][r], gf = acc[1][r], gg = acc[2][r], go = acc[3][r];
            float c = sigf(gf) * creg[r] + sigf(gi) * tanhf_fast(gg);
            creg[r] = c;
            hraw[s4 + r][j + 1] = sigf(go) * tanhf_fast(c);
        }
        __syncthreads();    // all GEMM A-reads done + hraw complete

        // S7: conv over hidden dim, h feedback + global writes
        int tslot = (k < 48) ? k : k - 1;
        int doW = (k != 48);
        int pslot = k - 49;
        #pragma unroll
        for (int r = 0; r < 4; ++r) {
            int s = s4 + r;
            float h = cw0 * hraw[s][j] + cw1 * hraw[s][j + 1] + cw2 * hraw[s][j + 2] + cb;
            A[s][128 + j] = f2b(h);
            if (doW) {
                size_t o = staged ? (((size_t)(s0 + s) * 64 + tslot) * 256 + j)
                                  : (((size_t)(s0 + s) * 256 + j) * 64 + tslot);
                Hd[o] = h;
                Cd[o] = creg[r];
            }
            if (pslot >= 0) predictb[((size_t)(s0 + s) * 16 + pslot) * 256 + j] = f2b(h);
        }
        // next iteration's first __syncthreads covers h/hraw ordering
    }
}

// ---------- staged [s][t][j] -> output [s][j][t] transpose ----------
__global__ __launch_bounds__(256) void transpose_k(const float* Hs, const float* Cs,
                                                   float* Ho, float* Co) {
    __shared__ float tile[64][129];
    int s = blockIdx.x, jh = blockIdx.y;
    const float* src = blockIdx.z ? Cs : Hs;
    float* dst = blockIdx.z ? Co : Ho;
    #pragma unroll 4
    for (int i = 0; i < 32; ++i) {
        int idx = i * 256 + threadIdx.x;
        int t = idx >> 7, jj = idx & 127;
        tile[t][jj] = src[((size_t)s * 64 + t) * 256 + jh * 128 + jj];
    }
    __syncthreads();
    #pragma unroll 4
    for (int i = 0; i < 32; ++i) {
        int idx = i * 256 + threadIdx.x;
        int jj = idx >> 6, t = idx & 63;
        dst[((size_t)s * 256 + jh * 128 + jj) * 64 + t] = tile[t][jj];
    }
}

// ---------- final: fc3 (64->1) + divide by laneC ----------
__global__ __launch_bounds__(256) void final_k(const short* t2b, const float* fW3, const float* fb3,
                                               const float* laneC, float* out0) {
    int r = blockIdx.x * 256 + threadIdx.x;
    float acc = fb3[0];
    const short* rowp = t2b + (size_t)r * 64;
    #pragma unroll 8
    for (int k = 0; k < 64; ++k) acc += b2f(rowp[k]) * fW3[k];
    out0[r] = acc / laneC[r >> 4];
}

// ---------- host ----------
extern "C" void kernel_launch(void* const* d_in, const int* in_sizes, int n_in,
                              void* d_out, int out_size, void* d_ws, size_t ws_size,
                              hipStream_t stream) {
    (void)in_sizes; (void)n_in; (void)out_size;
    const float* inputData = (const float*)d_in[0];
    const float* lane  = (const float*)d_in[1];
    const float* lgW1  = (const float*)d_in[2];  const float* lgb1 = (const float*)d_in[3];
    const float* lgW2  = (const float*)d_in[4];  const float* lgb2 = (const float*)d_in[5];
    const float* eW1   = (const float*)d_in[6];  const float* eb1  = (const float*)d_in[7];
    const float* eW2   = (const float*)d_in[8];  const float* eb2  = (const float*)d_in[9];
    const float* Wih   = (const float*)d_in[10]; const float* Whh  = (const float*)d_in[11];
    const float* bih   = (const float*)d_in[12]; const float* bhh  = (const float*)d_in[13];
    const float* convw = (const float*)d_in[14]; const float* convb= (const float*)d_in[15];
    const float* oW    = (const float*)d_in[16]; const float* ob   = (const float*)d_in[17];
    const float* fW1   = (const float*)d_in[18]; const float* fb1  = (const float*)d_in[19];
    const float* fW2   = (const float*)d_in[20]; const float* fb2  = (const float*)d_in[21];
    const float* fW3   = (const float*)d_in[22]; const float* fb3  = (const float*)d_in[23];

    float* out0 = (float*)d_out;
    float* Hout = out0 + 65536;
    float* Cout = Hout + (size_t)67108864;

    char* w = (char*)d_ws;
    size_t off = 0;
    auto alloc = [&](size_t bytes) -> void* {
        void* p = w + off;
        off += (bytes + 255) & ~(size_t)255;
        return p;
    };
    float* laneC    = (float*)alloc(4096 * 4);
    float* biasP    = (float*)alloc(1024 * 4);
    short* pW       = (short*)alloc((size_t)1024 * 384 * 2);
    short* oWp      = (short*)alloc((size_t)128 * 256 * 2);
    short* fW1p     = (short*)alloc((size_t)256 * 128 * 2);
    short* fW2p     = (short*)alloc((size_t)128 * 256 * 2);
    short* eW2p     = (short*)alloc((size_t)128 * 64 * 2);
    short* h1       = (short*)alloc((size_t)64 * 4096 * 64 * 2);
    short* xs       = (short*)alloc((size_t)64 * 4096 * 128 * 2);
    short* predictb = (short*)alloc((size_t)65536 * 256 * 2);
    short* t0b      = (short*)alloc((size_t)65536 * 128 * 2);
    short* t1b      = (short*)alloc((size_t)65536 * 256 * 2);
    short* t2b      = (short*)alloc((size_t)65536 * 64 * 2);
    float* Hstage   = (float*)alloc((size_t)4096 * 64 * 256 * 4);
    float* Cstage   = (float*)alloc((size_t)4096 * 64 * 256 * 4);
    bool staged = ws_size >= off;

    lanec_k<<<16, 256, 0, stream>>>(lane, lgW1, lgb1, lgW2, lgb2, laneC);
    {
        int total = 393216 + 1024 + 32768 + 32768 + 32768 + 8192;
        pack_k<<<(total + 255) / 256, 256, 0, stream>>>(Wih, Whh, bih, bhh, oW, fW1, fW2, eW2,
                                                        pW, biasP, oWp, fW1p, fW2p, eW2p);
    }
    embed1_k<<<65536, 256, 0, stream>>>(inputData, laneC, eW1, eb1, h1);
    gemm_k<<<dim3(2048, 1), 256, 0, stream>>>(h1, 64, (const short*)nullptr, 0, eW2p, 64,
                                              eb2, (float*)nullptr, xs, 128, 128, 1);

    float* Hd = staged ? Hstage : Hout;
    float* Cd = staged ? Cstage : Cout;
    lstm_k<<<256, 1024, 0, stream>>>(xs, pW, biasP, convw, convb, Hd, Cd, predictb,
                                     staged ? 1 : 0);
    if (staged)
        transpose_k<<<dim3(4096, 2, 2), 256, 0, stream>>>(Hstage, Cstage, Hout, Cout);

    gemm_k<<<dim3(512, 1), 256, 0, stream>>>(predictb, 256, (const short*)nullptr, 0, oWp, 256,
                                             ob, (float*)nullptr, t0b, 128, 128, 0);
    gemm_k<<<dim3(512, 2), 256, 0, stream>>>(t0b, 128, (const short*)nullptr, 0, fW1p, 128,
                                             fb1, (float*)nullptr, t1b, 256, 256, 1);
    gemm_k<<<dim3(512, 1), 256, 0, stream>>>(t1b, 256, (const short*)nullptr, 0, fW2p, 256,
                                             fb2, (float*)nullptr, t2b, 64, 64, 1);
    final_k<<<256, 256, 0, stream>>>(t2b, fW3, fb3, laneC, out0);
}